// Round 4
// baseline (1187.747 us; speedup 1.0000x reference)
//
#include <hip/hip_runtime.h>
#include <math.h>

#define NN 50000
#define NE 500000
#define HH 4
#define CC 64
#define HC 256
#define PD 16
#define XD 272
#define NEG 0.2f
#define MAXDEG 64   // direct bucket row stride; Poisson(10) over 50000 draws -> max deg ~30
#define NBLK (NN / 8)   // k_node blocks (8 nodes / block, 2 per wave)
#define GR 32       // k_gemm rows per tile (32 -> 1563 blocks, ~6 blocks/CU)

typedef _Float16 half4 __attribute__((ext_vector_type(4)));
typedef _Float16 half8 __attribute__((ext_vector_type(8)));
typedef float floatx4 __attribute__((ext_vector_type(4)));

#define ASTR 272   // LDS A row stride in halves (MFMA-read conflict-free)
#define CSTR 256   // LDS content-tile stride in halves (XOR-swizzled)

// ---------------- merged prep + edge bucketing (counts pre-zeroed by memset node) ----------------
// idx < 65536: wfrag swizzle. idx < NE: direct bucket placement.
// wfrag[(((kt*4+wv)*4+nt)*64 + lane)*8 + j] = W[wv*64+nt*16+(lane&15)][kt*32+(lane>>4)*8+j]
__global__ void k_pc(const float* __restrict__ w, _Float16* __restrict__ wfrag,
                     const int* __restrict__ row, const int* __restrict__ col,
                     int* __restrict__ counts, int* __restrict__ direct) {
    int idx = blockIdx.x * blockDim.x + threadIdx.x;
    if (idx < 65536) {
        int j = idx & 7, lane = (idx >> 3) & 63, nt = (idx >> 9) & 3;
        int wv = (idx >> 11) & 3, kt = idx >> 13;
        int n = wv * 64 + nt * 16 + (lane & 15);
        int k = kt * 32 + (lane >> 4) * 8 + j;
        wfrag[idx] = (_Float16)w[(size_t)n * 256 + k];
    }
    if (idx < NE) {
        int r = row[idx];
        int slot = atomicAdd(&counts[r], 1);
        if (slot < MAXDEG) direct[(size_t)r * MAXDEG + slot] = col[idx];
    }
}

// ---------------- MFMA GEMM: content(fp16) = Xc @ W^T, fused attention scores ----------------
// block = 256 thr (4 waves). Tile: 32 nodes x 256 cols; wave wv = head wv.
// 32-row tile: 1563 blocks (~6/CU), acc 2x4 (32 VGPR), LDS 17.4 KB -> 2x the
// resident waves of the 64-row version for the memory-bound staging phase.
__global__ __launch_bounds__(256) void k_gemm(const float* __restrict__ x,
                                              const _Float16* __restrict__ wfrag,
                                              const float* __restrict__ att,
                                              const float* __restrict__ patt,
                                              _Float16* __restrict__ content,
                                              float* __restrict__ ssrc,
                                              float* __restrict__ sdst) {
    __shared__ _Float16 As[GR * ASTR];   // 17408 B; reused as Ct[32][CSTR] (16384 B)
    const int tid = threadIdx.x;
    const int wv = tid >> 6, lane = tid & 63;
    const int nb = blockIdx.x * GR;
    const int m16 = lane & 15, q = lane >> 4;

    // ---- stage A: thread t -> row t>>3, k-base (t&7)*32 (32 floats -> fp16) ----
    {
        const int row = tid >> 3, kb = (tid & 7) * 32;
        int node = nb + row; if (node >= NN) node = NN - 1;   // clamp; stores guarded later
        const float* xp = &x[(size_t)node * XD + kb];
        _Float16* ap = &As[row * ASTR + kb];
#pragma unroll
        for (int i = 0; i < 4; i++) {
            float4 f0 = *(const float4*)(xp + i * 8);
            float4 f1 = *(const float4*)(xp + i * 8 + 4);
            half8 hv;
            hv[0] = (_Float16)f0.x; hv[1] = (_Float16)f0.y;
            hv[2] = (_Float16)f0.z; hv[3] = (_Float16)f0.w;
            hv[4] = (_Float16)f1.x; hv[5] = (_Float16)f1.y;
            hv[6] = (_Float16)f1.z; hv[7] = (_Float16)f1.w;
            *(half8*)(ap + i * 8) = hv;
        }
    }
    __syncthreads();

    floatx4 acc[2][4];
#pragma unroll
    for (int mt = 0; mt < 2; mt++)
#pragma unroll
        for (int nt = 0; nt < 4; nt++) acc[mt][nt] = (floatx4){0.f, 0.f, 0.f, 0.f};

#pragma unroll
    for (int kt = 0; kt < 8; kt++) {
        half8 bf[4];
#pragma unroll
        for (int nt = 0; nt < 4; nt++)
            bf[nt] = *(const half8*)&wfrag[((((size_t)kt * 4 + wv) * 4 + nt) * 64 + lane) * 8];
        half8 af[2];
#pragma unroll
        for (int mt = 0; mt < 2; mt++)
            af[mt] = *(half8*)&As[(mt * 16 + m16) * ASTR + kt * 32 + q * 8];
#pragma unroll
        for (int mt = 0; mt < 2; mt++)
#pragma unroll
            for (int nt = 0; nt < 4; nt++)
                acc[mt][nt] = __builtin_amdgcn_mfma_f32_16x16x32_f16(
                    af[mt], bf[nt], acc[mt][nt], 0, 0, 0);
    }

    __syncthreads();   // all As reads done; safe to overwrite with Ct

    // ---- acc -> LDS content tile, fp16, XOR-swizzled: col ^= (node&7)<<3 ----
    // D layout: col(in head) = nt*16 + m16, node = mt*16 + q*4 + r
    _Float16* Ct = As;
#pragma unroll
    for (int mt = 0; mt < 2; mt++) {
#pragma unroll
        for (int nt = 0; nt < 4; nt++) {
#pragma unroll
            for (int r = 0; r < 4; r++) {
                int nl = mt * 16 + q * 4 + r;
                int col = (wv * 64 + nt * 16 + m16) ^ ((nl & 7) << 3);
                Ct[nl * CSTR + col] = (_Float16)acc[mt][nt][r];
            }
        }
    }
    __syncthreads();

    // ---- vectorized content store: thread covers row wv*8+(lane>>3), 64-B seg lane&7 ----
    {
        const int rowl = wv * 8 + (lane >> 3), seg = lane & 7;
        const int node = nb + rowl;
        if (node < NN) {
            _Float16* cp = &content[(size_t)node * 256 + seg * 32];
#pragma unroll
            for (int i = 0; i < 4; i++) {
                int colb = (seg * 32 + i * 8) ^ ((rowl & 7) << 3);
                *(half8*)(cp + i * 8) = *(const half8*)&Ct[rowl * CSTR + colb];
            }
        }
    }

    // ---- scores: lanes 0-31 -> sa for node el, lanes 32-63 -> sb for node el ----
    {
        const int el = lane & 31, hb = lane >> 5;
        const int node = nb + el;
        float s = 0.f;
        const float* ap = &att[wv * 128 + hb * 64];
#pragma unroll
        for (int i = 0; i < 8; i++) {
            int colb = (wv * 64 + i * 8) ^ ((el & 7) << 3);
            half8 v = *(const half8*)&Ct[el * CSTR + colb];
#pragma unroll
            for (int j = 0; j < 8; j++) s += (float)v[j] * ap[i * 8 + j];
        }
        const int rn = node < NN ? node : NN - 1;
        const float* xp = &x[(size_t)rn * XD + 256];
        const float* pp = &patt[wv * 32 + hb * 16];
#pragma unroll
        for (int p4 = 0; p4 < 4; p4++) {
            float4 pv = *(const float4*)(xp + p4 * 4);
            s += pv.x * pp[p4 * 4 + 0] + pv.y * pp[p4 * 4 + 1]
               + pv.z * pp[p4 * 4 + 2] + pv.w * pp[p4 * 4 + 3];
        }
        if (node < NN) {
            float* dst = hb ? sdst : ssrc;
            dst[node * 4 + wv] = s;
        }
    }
}

// ---------------- per-node softmax + aggregation (2 nodes / wave, 32 lanes each) ----------------
// Node A = lanes 0-31, node B = lanes 32-63. Gathers are half8 (16 B/lane).
// Software pipeline: batch-0 gathers issued BEFORE the softmax math; agg loop
// prefetches batch k+1 while FMA-ing batch k (8 rows in flight/wave).
// Last finishing block performs the gram reduction + diversity loss (k_final fused).
__global__ __launch_bounds__(256) void k_node(const _Float16* __restrict__ content,
                                              const float* __restrict__ ssrc,
                                              const float* __restrict__ sdst,
                                              const int* __restrict__ counts,
                                              const int* __restrict__ direct,
                                              const float* __restrict__ bias,
                                              float* __restrict__ out,
                                              float* __restrict__ gpart,
                                              int* __restrict__ done,
                                              float* __restrict__ dv) {
    __shared__ float gsh[16];
    __shared__ __align__(16) float ash[4][2][4][32];  // [wave][half][head][edge]; reused as fs[256]
    __shared__ __align__(16) int   csh[4][2][32];     // per-half col cache
    const int w = threadIdx.x >> 6;
    const int lane = threadIdx.x & 63;
    const int h2 = lane >> 5, el = lane & 31;
    const int nb2 = blockIdx.x * 8 + w * 2;   // NN % 8 == 0
    if (threadIdx.x < 16) gsh[threadIdx.x] = 0.f;
    __syncthreads();

    const int n = nb2 + h2;
    const int cnt = counts[n];              // broadcast 4B load per half

    float g[10];
#pragma unroll
    for (int k = 0; k < 10; k++) g[k] = 0.f;

    if (__all(cnt < 32)) {
        // ---- fast path: one edge per lane within each 32-lane half ----
        const int tot = cnt + 1;                 // + self loop
        const bool act = el < tot;
        const int c = (el < cnt) ? direct[(size_t)n * MAXDEG + el] : n;  // pad = self
        csh[w][h2][el] = c;                      // publish indices FIRST

        // issue batch-0 gathers before softmax math (latency overlap)
        const half8* c8 = (const half8*)content;
        const int4 ca0 = *(const int4*)&csh[w][h2][0];
        half8 v0 = c8[(size_t)ca0.x * 32 + el];
        half8 v1 = c8[(size_t)ca0.y * 32 + el];
        half8 v2 = c8[(size_t)ca0.z * 32 + el];
        half8 v3 = c8[(size_t)ca0.w * 32 + el];

        const float4 ss = *(const float4*)&ssrc[n * 4];
        const float4 sd = *(const float4*)&sdst[c * 4];
        float r0 = ss.x + sd.x; r0 = r0 > 0.f ? r0 : NEG * r0;
        float r1 = ss.y + sd.y; r1 = r1 > 0.f ? r1 : NEG * r1;
        float r2 = ss.z + sd.z; r2 = r2 > 0.f ? r2 : NEG * r2;
        float r3 = ss.w + sd.w; r3 = r3 > 0.f ? r3 : NEG * r3;
        float e0 = act ? __expf(r0) : 0.f;       // no max-subtract: |r| bounded
        float e1 = act ? __expf(r1) : 0.f;
        float e2 = act ? __expf(r2) : 0.f;
        float e3 = act ? __expf(r3) : 0.f;
        float s0 = e0, s1 = e1, s2 = e2, s3 = e3;
#pragma unroll
        for (int s = 1; s < 32; s <<= 1) {      // within-half reduce
            s0 += __shfl_xor(s0, s); s1 += __shfl_xor(s1, s);
            s2 += __shfl_xor(s2, s); s3 += __shfl_xor(s3, s);
        }
        const float a0 = e0 / (s0 + 1e-16f), a1 = e1 / (s1 + 1e-16f);
        const float a2 = e2 / (s2 + 1e-16f), a3 = e3 / (s3 + 1e-16f);

        g[0] = a0 * a0; g[1] = a0 * a1; g[2] = a0 * a2; g[3] = a0 * a3;
        g[4] = a1 * a1; g[5] = a1 * a2; g[6] = a1 * a3;
        g[7] = a2 * a2; g[8] = a2 * a3; g[9] = a3 * a3;

        ash[w][h2][0][el] = a0; ash[w][h2][1][el] = a1;
        ash[w][h2][2][el] = a2; ash[w][h2][3][el] = a3;

        // ---- aggregation: lane covers channels el*8..el*8+7; prefetch next batch ----
        const int hd = el >> 3;
        float acc[8];
#pragma unroll
        for (int j = 0; j < 8; j++) acc[j] = 0.f;

        const int nit = (tot + 3) & ~3;
        for (int e = 0; e < nit; e += 4) {
            const half8 w0 = v0, w1 = v1, w2 = v2, w3 = v3;
            if (e + 4 < nit) {
                const int4 cn = *(const int4*)&csh[w][h2][e + 4];
                v0 = c8[(size_t)cn.x * 32 + el];
                v1 = c8[(size_t)cn.y * 32 + el];
                v2 = c8[(size_t)cn.z * 32 + el];
                v3 = c8[(size_t)cn.w * 32 + el];
            }
            const float4 ba = *(const float4*)&ash[w][h2][hd][e];
#pragma unroll
            for (int j = 0; j < 8; j++)
                acc[j] += ba.x * (float)w0[j] + ba.y * (float)w1[j]
                        + ba.z * (float)w2[j] + ba.w * (float)w3[j];
        }

        const float4 bv0 = ((const float4*)bias)[el * 2];
        const float4 bv1 = ((const float4*)bias)[el * 2 + 1];
        float4 o0, o1;
        o0.x = acc[0] + bv0.x; o0.y = acc[1] + bv0.y;
        o0.z = acc[2] + bv0.z; o0.w = acc[3] + bv0.w;
        o1.x = acc[4] + bv1.x; o1.y = acc[5] + bv1.y;
        o1.z = acc[6] + bv1.z; o1.w = acc[7] + bv1.w;
        ((float4*)out)[(size_t)n * 64 + el * 2] = o0;
        ((float4*)out)[(size_t)n * 64 + el * 2 + 1] = o1;
    } else {
        // ---- generic chunked path (degree >= 32; essentially never) ----
        // whole wave processes each of the 2 nodes sequentially
        const int hsel = lane >> 4;
        const half4* c4 = (const half4*)content;
        for (int sN = 0; sN < 2; sN++) {
            const int nn = nb2 + sN;
            int cnt2 = counts[nn]; if (cnt2 > MAXDEG) cnt2 = MAXDEG;
            const int total = cnt2 + 1;
            const size_t base2 = (size_t)nn * MAXDEG;
            const float4 ss = *(const float4*)&ssrc[nn * 4];
            float4 acc = make_float4(0.f, 0.f, 0.f, 0.f);
            const int nch = (total + 63) >> 6;
            float m0 = -1e30f, m1 = -1e30f, m2 = -1e30f, m3 = -1e30f;
            for (int ch = 0; ch < nch; ch++) {
                int l = ch * 64 + lane;
                if (l < total) {
                    int c = (l < cnt2) ? direct[base2 + l] : nn;
                    float4 sd = *(const float4*)&sdst[c * 4];
                    float r0 = ss.x + sd.x; r0 = r0 > 0.f ? r0 : NEG * r0;
                    float r1 = ss.y + sd.y; r1 = r1 > 0.f ? r1 : NEG * r1;
                    float r2 = ss.z + sd.z; r2 = r2 > 0.f ? r2 : NEG * r2;
                    float r3 = ss.w + sd.w; r3 = r3 > 0.f ? r3 : NEG * r3;
                    m0 = fmaxf(m0, r0); m1 = fmaxf(m1, r1);
                    m2 = fmaxf(m2, r2); m3 = fmaxf(m3, r3);
                }
            }
#pragma unroll
            for (int s = 1; s < 64; s <<= 1) {
                m0 = fmaxf(m0, __shfl_xor(m0, s));
                m1 = fmaxf(m1, __shfl_xor(m1, s));
                m2 = fmaxf(m2, __shfl_xor(m2, s));
                m3 = fmaxf(m3, __shfl_xor(m3, s));
            }
            float s0 = 0.f, s1 = 0.f, s2 = 0.f, s3 = 0.f;
            for (int ch = 0; ch < nch; ch++) {
                int l = ch * 64 + lane;
                if (l < total) {
                    int c = (l < cnt2) ? direct[base2 + l] : nn;
                    float4 sd = *(const float4*)&sdst[c * 4];
                    float r0 = ss.x + sd.x; r0 = r0 > 0.f ? r0 : NEG * r0;
                    float r1 = ss.y + sd.y; r1 = r1 > 0.f ? r1 : NEG * r1;
                    float r2 = ss.z + sd.z; r2 = r2 > 0.f ? r2 : NEG * r2;
                    float r3 = ss.w + sd.w; r3 = r3 > 0.f ? r3 : NEG * r3;
                    s0 += __expf(r0 - m0); s1 += __expf(r1 - m1);
                    s2 += __expf(r2 - m2); s3 += __expf(r3 - m3);
                }
            }
#pragma unroll
            for (int s = 1; s < 64; s <<= 1) {
                s0 += __shfl_xor(s0, s); s1 += __shfl_xor(s1, s);
                s2 += __shfl_xor(s2, s); s3 += __shfl_xor(s3, s);
            }
            const float i0 = 1.f / (s0 + 1e-16f), i1 = 1.f / (s1 + 1e-16f);
            const float i2 = 1.f / (s2 + 1e-16f), i3 = 1.f / (s3 + 1e-16f);

            for (int ch = 0; ch < nch; ch++) {
                int l = ch * 64 + lane;
                int c = nn;
                float a0 = 0.f, a1 = 0.f, a2 = 0.f, a3 = 0.f;
                if (l < total) {
                    c = (l < cnt2) ? direct[base2 + l] : nn;
                    float4 sd = *(const float4*)&sdst[c * 4];
                    float r0 = ss.x + sd.x; r0 = r0 > 0.f ? r0 : NEG * r0;
                    float r1 = ss.y + sd.y; r1 = r1 > 0.f ? r1 : NEG * r1;
                    float r2 = ss.z + sd.z; r2 = r2 > 0.f ? r2 : NEG * r2;
                    float r3 = ss.w + sd.w; r3 = r3 > 0.f ? r3 : NEG * r3;
                    a0 = __expf(r0 - m0) * i0; a1 = __expf(r1 - m1) * i1;
                    a2 = __expf(r2 - m2) * i2; a3 = __expf(r3 - m3) * i3;
                }
                g[0] += a0 * a0; g[1] += a0 * a1; g[2] += a0 * a2; g[3] += a0 * a3;
                g[4] += a1 * a1; g[5] += a1 * a2; g[6] += a1 * a3;
                g[7] += a2 * a2; g[8] += a2 * a3; g[9] += a3 * a3;

                int cc = min(64, total - ch * 64);
                for (int e = 0; e < cc; e++) {
                    float b0 = __shfl(a0, e), b1 = __shfl(a1, e);
                    float b2 = __shfl(a2, e), b3 = __shfl(a3, e);
                    int ce = __shfl(c, e);
                    float mya = hsel == 0 ? b0 : hsel == 1 ? b1 : hsel == 2 ? b2 : b3;
                    half4 cv = c4[(size_t)ce * 64 + lane];
                    acc.x += mya * (float)cv[0]; acc.y += mya * (float)cv[1];
                    acc.z += mya * (float)cv[2]; acc.w += mya * (float)cv[3];
                }
            }
            float4 bv = ((const float4*)bias)[lane];
            acc.x += bv.x; acc.y += bv.y; acc.z += bv.z; acc.w += bv.w;
            ((float4*)out)[(size_t)nn * 64 + lane] = acc;
        }
    }

    // gram: 6-stage wave reduce merges both halves (contributions are additive)
#pragma unroll
    for (int s = 1; s < 64; s <<= 1) {
#pragma unroll
        for (int k = 0; k < 10; k++) g[k] += __shfl_xor(g[k], s);
    }
    if (lane == 0) {
#pragma unroll
        for (int k = 0; k < 10; k++) atomicAdd(&gsh[k], g[k]);
    }
    __syncthreads();
    if (threadIdx.x < 10) gpart[(size_t)blockIdx.x * 10 + threadIdx.x] = gsh[threadIdx.x];

    // ---- fused k_final: last finishing block reduces gram partials (device-scope) ----
    __threadfence();   // release: gpart writes visible device-wide before the atomic
    if (threadIdx.x == 0) gsh[15] = (atomicAdd(done, 1) == NBLK - 1) ? 1.f : 0.f;
    __syncthreads();
    if (gsh[15] != 0.f) {
        __threadfence();   // acquire: see all other blocks' gpart writes
        float* fs = &ash[0][0][0][0];   // reuse 1024-float LDS as fs[256]
        const int k = threadIdx.x & 15, grp = threadIdx.x >> 4;   // 16 groups x 16 slots
        float v = 0.f;
        if (k < 10) {
            const volatile float* gp = gpart;
            for (int b = grp; b < NBLK; b += 16) v += gp[(size_t)b * 10 + k];
        }
        fs[threadIdx.x] = v;
        __syncthreads();
        for (int off = 128; off >= 16; off >>= 1) {
            if (threadIdx.x < off) fs[threadIdx.x] += fs[threadIdx.x + off];
            __syncthreads();
        }
        if (threadIdx.x == 0) {
            float g00 = fs[0], g01 = fs[1], g02 = fs[2], g03 = fs[3];
            float g11 = fs[4], g12 = fs[5], g13 = fs[6];
            float g22 = fs[7], g23 = fs[8], g33 = fs[9];
            float n0 = fmaxf(sqrtf(g00), 1e-8f), n1 = fmaxf(sqrtf(g11), 1e-8f);
            float n2 = fmaxf(sqrtf(g22), 1e-8f), n3 = fmaxf(sqrtf(g33), 1e-8f);
            float sum = g01 / (n0 * n1) + g02 / (n0 * n2) + g03 / (n0 * n3) +
                        g12 / (n1 * n2) + g13 / (n1 * n3) + g23 / (n2 * n3);
            sum *= 2.0f;
            dv[0] = sum / 16.0f * 0.1f;
        }
    }
}

extern "C" void kernel_launch(void* const* d_in, const int* in_sizes, int n_in,
                              void* d_out, int out_size, void* d_ws, size_t ws_size,
                              hipStream_t stream) {
    const float* x    = (const float*)d_in[0];
    const int*   ei   = (const int*)d_in[1];
    const int*   row  = ei;
    const int*   col  = ei + NE;
    const float* w    = (const float*)d_in[2];
    const float* att  = (const float*)d_in[3];
    const float* patt = (const float*)d_in[4];
    const float* bias = (const float*)d_in[5];
    float* out = (float*)d_out;

    char* p = (char*)d_ws;
    _Float16* content = (_Float16*)p; p += (size_t)NN * 256 * 2;
    _Float16* wfrag   = (_Float16*)p; p += (size_t)256 * 256 * 2;
    float* ssrc    = (float*)p; p += (size_t)NN * 4 * 4;
    float* sdst    = (float*)p; p += (size_t)NN * 4 * 4;
    float* gpart   = (float*)p; p += (size_t)NBLK * 10 * 4;
    int* counts    = (int*)p;   p += (size_t)NN * 4;
    int* done      = (int*)p;   p += 64;            // contiguous with counts: one memset
    int* direct    = (int*)p;   p += (size_t)NN * MAXDEG * 4;

    // zero counts + done in one graph-capturable memset node
    hipMemsetAsync(counts, 0, (size_t)NN * 4 + 64, stream);

    k_pc<<<(NE + 255) / 256, 256, 0, stream>>>(w, wfrag, row, col, counts, direct);

    k_gemm<<<(NN + GR - 1) / GR, 256, 0, stream>>>(x, wfrag, att, patt, content, ssrc, sdst);

    k_node<<<NBLK, 256, 0, stream>>>(content, ssrc, sdst, counts, direct,
                                     bias, out, gpart, done, out + (size_t)NN * 256);
}

// Round 5
// 231.755 us; speedup vs baseline: 5.1250x; 5.1250x over previous
//
#include <hip/hip_runtime.h>
#include <math.h>

#define NN 50000
#define NE 500000
#define HH 4
#define CC 64
#define HC 256
#define PD 16
#define XD 272
#define NEG 0.2f
#define MAXDEG 64   // direct bucket row stride; Poisson(10) over 50000 draws -> max deg ~30
#define NBLK (NN / 8)   // k_node blocks (8 nodes / block, 2 per wave)
#define GR 32       // k_gemm rows per tile (32 -> 1563 blocks, ~6 blocks/CU)

typedef _Float16 half4 __attribute__((ext_vector_type(4)));
typedef _Float16 half8 __attribute__((ext_vector_type(8)));
typedef float floatx4 __attribute__((ext_vector_type(4)));

#define ASTR 272   // LDS A row stride in halves (MFMA-read conflict-free)
#define CSTR 256   // LDS content-tile stride in halves (XOR-swizzled)

// ---------------- merged prep + edge bucketing (counts pre-zeroed by memset node) ----------------
// idx < 65536: wfrag swizzle. idx < NE: direct bucket placement.
// wfrag[(((kt*4+wv)*4+nt)*64 + lane)*8 + j] = W[wv*64+nt*16+(lane&15)][kt*32+(lane>>4)*8+j]
__global__ void k_pc(const float* __restrict__ w, _Float16* __restrict__ wfrag,
                     const int* __restrict__ row, const int* __restrict__ col,
                     int* __restrict__ counts, int* __restrict__ direct) {
    int idx = blockIdx.x * blockDim.x + threadIdx.x;
    if (idx < 65536) {
        int j = idx & 7, lane = (idx >> 3) & 63, nt = (idx >> 9) & 3;
        int wv = (idx >> 11) & 3, kt = idx >> 13;
        int n = wv * 64 + nt * 16 + (lane & 15);
        int k = kt * 32 + (lane >> 4) * 8 + j;
        wfrag[idx] = (_Float16)w[(size_t)n * 256 + k];
    }
    if (idx < NE) {
        int r = row[idx];
        int slot = atomicAdd(&counts[r], 1);
        if (slot < MAXDEG) direct[(size_t)r * MAXDEG + slot] = col[idx];
    }
}

// ---------------- MFMA GEMM: content(fp16) = Xc @ W^T, fused attention scores ----------------
// block = 256 thr (4 waves). Tile: 32 nodes x 256 cols; wave wv = head wv.
// 32-row tile: 1563 blocks (~6/CU), acc 2x4 (32 VGPR), LDS 17.4 KB.
__global__ __launch_bounds__(256) void k_gemm(const float* __restrict__ x,
                                              const _Float16* __restrict__ wfrag,
                                              const float* __restrict__ att,
                                              const float* __restrict__ patt,
                                              _Float16* __restrict__ content,
                                              float* __restrict__ ssrc,
                                              float* __restrict__ sdst) {
    __shared__ _Float16 As[GR * ASTR];   // 17408 B; reused as Ct[32][CSTR] (16384 B)
    const int tid = threadIdx.x;
    const int wv = tid >> 6, lane = tid & 63;
    const int nb = blockIdx.x * GR;
    const int m16 = lane & 15, q = lane >> 4;

    // ---- stage A: thread t -> row t>>3, k-base (t&7)*32 (32 floats -> fp16) ----
    {
        const int row = tid >> 3, kb = (tid & 7) * 32;
        int node = nb + row; if (node >= NN) node = NN - 1;   // clamp; stores guarded later
        const float* xp = &x[(size_t)node * XD + kb];
        _Float16* ap = &As[row * ASTR + kb];
#pragma unroll
        for (int i = 0; i < 4; i++) {
            float4 f0 = *(const float4*)(xp + i * 8);
            float4 f1 = *(const float4*)(xp + i * 8 + 4);
            half8 hv;
            hv[0] = (_Float16)f0.x; hv[1] = (_Float16)f0.y;
            hv[2] = (_Float16)f0.z; hv[3] = (_Float16)f0.w;
            hv[4] = (_Float16)f1.x; hv[5] = (_Float16)f1.y;
            hv[6] = (_Float16)f1.z; hv[7] = (_Float16)f1.w;
            *(half8*)(ap + i * 8) = hv;
        }
    }
    __syncthreads();

    floatx4 acc[2][4];
#pragma unroll
    for (int mt = 0; mt < 2; mt++)
#pragma unroll
        for (int nt = 0; nt < 4; nt++) acc[mt][nt] = (floatx4){0.f, 0.f, 0.f, 0.f};

#pragma unroll
    for (int kt = 0; kt < 8; kt++) {
        half8 bf[4];
#pragma unroll
        for (int nt = 0; nt < 4; nt++)
            bf[nt] = *(const half8*)&wfrag[((((size_t)kt * 4 + wv) * 4 + nt) * 64 + lane) * 8];
        half8 af[2];
#pragma unroll
        for (int mt = 0; mt < 2; mt++)
            af[mt] = *(half8*)&As[(mt * 16 + m16) * ASTR + kt * 32 + q * 8];
#pragma unroll
        for (int mt = 0; mt < 2; mt++)
#pragma unroll
            for (int nt = 0; nt < 4; nt++)
                acc[mt][nt] = __builtin_amdgcn_mfma_f32_16x16x32_f16(
                    af[mt], bf[nt], acc[mt][nt], 0, 0, 0);
    }

    __syncthreads();   // all As reads done; safe to overwrite with Ct

    // ---- acc -> LDS content tile, fp16, XOR-swizzled: col ^= (node&7)<<3 ----
    // D layout: col(in head) = nt*16 + m16, node = mt*16 + q*4 + r
    _Float16* Ct = As;
#pragma unroll
    for (int mt = 0; mt < 2; mt++) {
#pragma unroll
        for (int nt = 0; nt < 4; nt++) {
#pragma unroll
            for (int r = 0; r < 4; r++) {
                int nl = mt * 16 + q * 4 + r;
                int col = (wv * 64 + nt * 16 + m16) ^ ((nl & 7) << 3);
                Ct[nl * CSTR + col] = (_Float16)acc[mt][nt][r];
            }
        }
    }
    __syncthreads();

    // ---- vectorized content store: thread covers row wv*8+(lane>>3), 64-B seg lane&7 ----
    {
        const int rowl = wv * 8 + (lane >> 3), seg = lane & 7;
        const int node = nb + rowl;
        if (node < NN) {
            _Float16* cp = &content[(size_t)node * 256 + seg * 32];
#pragma unroll
            for (int i = 0; i < 4; i++) {
                int colb = (seg * 32 + i * 8) ^ ((rowl & 7) << 3);
                *(half8*)(cp + i * 8) = *(const half8*)&Ct[rowl * CSTR + colb];
            }
        }
    }

    // ---- scores: lanes 0-31 -> sa for node el, lanes 32-63 -> sb for node el ----
    {
        const int el = lane & 31, hb = lane >> 5;
        const int node = nb + el;
        float s = 0.f;
        const float* ap = &att[wv * 128 + hb * 64];
#pragma unroll
        for (int i = 0; i < 8; i++) {
            int colb = (wv * 64 + i * 8) ^ ((el & 7) << 3);
            half8 v = *(const half8*)&Ct[el * CSTR + colb];
#pragma unroll
            for (int j = 0; j < 8; j++) s += (float)v[j] * ap[i * 8 + j];
        }
        const int rn = node < NN ? node : NN - 1;
        const float* xp = &x[(size_t)rn * XD + 256];
        const float* pp = &patt[wv * 32 + hb * 16];
#pragma unroll
        for (int p4 = 0; p4 < 4; p4++) {
            float4 pv = *(const float4*)(xp + p4 * 4);
            s += pv.x * pp[p4 * 4 + 0] + pv.y * pp[p4 * 4 + 1]
               + pv.z * pp[p4 * 4 + 2] + pv.w * pp[p4 * 4 + 3];
        }
        if (node < NN) {
            float* dst = hb ? sdst : ssrc;
            dst[node * 4 + wv] = s;
        }
    }
}

// ---------------- per-node softmax + aggregation (2 nodes / wave, 32 lanes each) ----------------
// Node A = lanes 0-31, node B = lanes 32-63. Gathers are half8 (16 B/lane).
// Software pipeline: batch-0 gathers issued BEFORE the softmax math; agg loop
// prefetches batch k+1 while FMA-ing batch k (8 rows in flight/wave).
// NOTE (R4 lesson): do NOT fuse the gram finalization here via last-block +
// __threadfence() — a device-scope fence in all 6250 blocks serialized the L2
// writeback path and cost ~900 us. Separate 1-block k_final is ~free.
__global__ __launch_bounds__(256) void k_node(const _Float16* __restrict__ content,
                                              const float* __restrict__ ssrc,
                                              const float* __restrict__ sdst,
                                              const int* __restrict__ counts,
                                              const int* __restrict__ direct,
                                              const float* __restrict__ bias,
                                              float* __restrict__ out,
                                              float* __restrict__ gpart) {
    __shared__ float gsh[16];
    __shared__ __align__(16) float ash[4][2][4][32];  // [wave][half][head][edge]
    __shared__ __align__(16) int   csh[4][2][32];     // per-half col cache
    const int w = threadIdx.x >> 6;
    const int lane = threadIdx.x & 63;
    const int h2 = lane >> 5, el = lane & 31;
    const int nb2 = blockIdx.x * 8 + w * 2;   // NN % 8 == 0
    if (threadIdx.x < 16) gsh[threadIdx.x] = 0.f;
    __syncthreads();

    const int n = nb2 + h2;
    const int cnt = counts[n];              // broadcast 4B load per half

    float g[10];
#pragma unroll
    for (int k = 0; k < 10; k++) g[k] = 0.f;

    if (__all(cnt < 32)) {
        // ---- fast path: one edge per lane within each 32-lane half ----
        const int tot = cnt + 1;                 // + self loop
        const bool act = el < tot;
        const int c = (el < cnt) ? direct[(size_t)n * MAXDEG + el] : n;  // pad = self
        csh[w][h2][el] = c;                      // publish indices FIRST

        // issue batch-0 gathers before softmax math (latency overlap)
        const half8* c8 = (const half8*)content;
        const int4 ca0 = *(const int4*)&csh[w][h2][0];
        half8 v0 = c8[(size_t)ca0.x * 32 + el];
        half8 v1 = c8[(size_t)ca0.y * 32 + el];
        half8 v2 = c8[(size_t)ca0.z * 32 + el];
        half8 v3 = c8[(size_t)ca0.w * 32 + el];

        const float4 ss = *(const float4*)&ssrc[n * 4];
        const float4 sd = *(const float4*)&sdst[c * 4];
        float r0 = ss.x + sd.x; r0 = r0 > 0.f ? r0 : NEG * r0;
        float r1 = ss.y + sd.y; r1 = r1 > 0.f ? r1 : NEG * r1;
        float r2 = ss.z + sd.z; r2 = r2 > 0.f ? r2 : NEG * r2;
        float r3 = ss.w + sd.w; r3 = r3 > 0.f ? r3 : NEG * r3;
        float e0 = act ? __expf(r0) : 0.f;       // no max-subtract: |r| bounded
        float e1 = act ? __expf(r1) : 0.f;
        float e2 = act ? __expf(r2) : 0.f;
        float e3 = act ? __expf(r3) : 0.f;
        float s0 = e0, s1 = e1, s2 = e2, s3 = e3;
#pragma unroll
        for (int s = 1; s < 32; s <<= 1) {      // within-half reduce
            s0 += __shfl_xor(s0, s); s1 += __shfl_xor(s1, s);
            s2 += __shfl_xor(s2, s); s3 += __shfl_xor(s3, s);
        }
        const float a0 = e0 / (s0 + 1e-16f), a1 = e1 / (s1 + 1e-16f);
        const float a2 = e2 / (s2 + 1e-16f), a3 = e3 / (s3 + 1e-16f);

        g[0] = a0 * a0; g[1] = a0 * a1; g[2] = a0 * a2; g[3] = a0 * a3;
        g[4] = a1 * a1; g[5] = a1 * a2; g[6] = a1 * a3;
        g[7] = a2 * a2; g[8] = a2 * a3; g[9] = a3 * a3;

        ash[w][h2][0][el] = a0; ash[w][h2][1][el] = a1;
        ash[w][h2][2][el] = a2; ash[w][h2][3][el] = a3;

        // ---- aggregation: lane covers channels el*8..el*8+7; prefetch next batch ----
        const int hd = el >> 3;
        float acc[8];
#pragma unroll
        for (int j = 0; j < 8; j++) acc[j] = 0.f;

        const int nit = (tot + 3) & ~3;
        for (int e = 0; e < nit; e += 4) {
            const half8 w0 = v0, w1 = v1, w2 = v2, w3 = v3;
            if (e + 4 < nit) {
                const int4 cn = *(const int4*)&csh[w][h2][e + 4];
                v0 = c8[(size_t)cn.x * 32 + el];
                v1 = c8[(size_t)cn.y * 32 + el];
                v2 = c8[(size_t)cn.z * 32 + el];
                v3 = c8[(size_t)cn.w * 32 + el];
            }
            const float4 ba = *(const float4*)&ash[w][h2][hd][e];
#pragma unroll
            for (int j = 0; j < 8; j++)
                acc[j] += ba.x * (float)w0[j] + ba.y * (float)w1[j]
                        + ba.z * (float)w2[j] + ba.w * (float)w3[j];
        }

        const float4 bv0 = ((const float4*)bias)[el * 2];
        const float4 bv1 = ((const float4*)bias)[el * 2 + 1];
        float4 o0, o1;
        o0.x = acc[0] + bv0.x; o0.y = acc[1] + bv0.y;
        o0.z = acc[2] + bv0.z; o0.w = acc[3] + bv0.w;
        o1.x = acc[4] + bv1.x; o1.y = acc[5] + bv1.y;
        o1.z = acc[6] + bv1.z; o1.w = acc[7] + bv1.w;
        ((float4*)out)[(size_t)n * 64 + el * 2] = o0;
        ((float4*)out)[(size_t)n * 64 + el * 2 + 1] = o1;
    } else {
        // ---- generic chunked path (degree >= 32; essentially never) ----
        // whole wave processes each of the 2 nodes sequentially
        const int hsel = lane >> 4;
        const half4* c4 = (const half4*)content;
        for (int sN = 0; sN < 2; sN++) {
            const int nn = nb2 + sN;
            int cnt2 = counts[nn]; if (cnt2 > MAXDEG) cnt2 = MAXDEG;
            const int total = cnt2 + 1;
            const size_t base2 = (size_t)nn * MAXDEG;
            const float4 ss = *(const float4*)&ssrc[nn * 4];
            float4 acc = make_float4(0.f, 0.f, 0.f, 0.f);
            const int nch = (total + 63) >> 6;
            float m0 = -1e30f, m1 = -1e30f, m2 = -1e30f, m3 = -1e30f;
            for (int ch = 0; ch < nch; ch++) {
                int l = ch * 64 + lane;
                if (l < total) {
                    int c = (l < cnt2) ? direct[base2 + l] : nn;
                    float4 sd = *(const float4*)&sdst[c * 4];
                    float r0 = ss.x + sd.x; r0 = r0 > 0.f ? r0 : NEG * r0;
                    float r1 = ss.y + sd.y; r1 = r1 > 0.f ? r1 : NEG * r1;
                    float r2 = ss.z + sd.z; r2 = r2 > 0.f ? r2 : NEG * r2;
                    float r3 = ss.w + sd.w; r3 = r3 > 0.f ? r3 : NEG * r3;
                    m0 = fmaxf(m0, r0); m1 = fmaxf(m1, r1);
                    m2 = fmaxf(m2, r2); m3 = fmaxf(m3, r3);
                }
            }
#pragma unroll
            for (int s = 1; s < 64; s <<= 1) {
                m0 = fmaxf(m0, __shfl_xor(m0, s));
                m1 = fmaxf(m1, __shfl_xor(m1, s));
                m2 = fmaxf(m2, __shfl_xor(m2, s));
                m3 = fmaxf(m3, __shfl_xor(m3, s));
            }
            float s0 = 0.f, s1 = 0.f, s2 = 0.f, s3 = 0.f;
            for (int ch = 0; ch < nch; ch++) {
                int l = ch * 64 + lane;
                if (l < total) {
                    int c = (l < cnt2) ? direct[base2 + l] : nn;
                    float4 sd = *(const float4*)&sdst[c * 4];
                    float r0 = ss.x + sd.x; r0 = r0 > 0.f ? r0 : NEG * r0;
                    float r1 = ss.y + sd.y; r1 = r1 > 0.f ? r1 : NEG * r1;
                    float r2 = ss.z + sd.z; r2 = r2 > 0.f ? r2 : NEG * r2;
                    float r3 = ss.w + sd.w; r3 = r3 > 0.f ? r3 : NEG * r3;
                    s0 += __expf(r0 - m0); s1 += __expf(r1 - m1);
                    s2 += __expf(r2 - m2); s3 += __expf(r3 - m3);
                }
            }
#pragma unroll
            for (int s = 1; s < 64; s <<= 1) {
                s0 += __shfl_xor(s0, s); s1 += __shfl_xor(s1, s);
                s2 += __shfl_xor(s2, s); s3 += __shfl_xor(s3, s);
            }
            const float i0 = 1.f / (s0 + 1e-16f), i1 = 1.f / (s1 + 1e-16f);
            const float i2 = 1.f / (s2 + 1e-16f), i3 = 1.f / (s3 + 1e-16f);

            for (int ch = 0; ch < nch; ch++) {
                int l = ch * 64 + lane;
                int c = nn;
                float a0 = 0.f, a1 = 0.f, a2 = 0.f, a3 = 0.f;
                if (l < total) {
                    c = (l < cnt2) ? direct[base2 + l] : nn;
                    float4 sd = *(const float4*)&sdst[c * 4];
                    float r0 = ss.x + sd.x; r0 = r0 > 0.f ? r0 : NEG * r0;
                    float r1 = ss.y + sd.y; r1 = r1 > 0.f ? r1 : NEG * r1;
                    float r2 = ss.z + sd.z; r2 = r2 > 0.f ? r2 : NEG * r2;
                    float r3 = ss.w + sd.w; r3 = r3 > 0.f ? r3 : NEG * r3;
                    a0 = __expf(r0 - m0) * i0; a1 = __expf(r1 - m1) * i1;
                    a2 = __expf(r2 - m2) * i2; a3 = __expf(r3 - m3) * i3;
                }
                g[0] += a0 * a0; g[1] += a0 * a1; g[2] += a0 * a2; g[3] += a0 * a3;
                g[4] += a1 * a1; g[5] += a1 * a2; g[6] += a1 * a3;
                g[7] += a2 * a2; g[8] += a2 * a3; g[9] += a3 * a3;

                int cc = min(64, total - ch * 64);
                for (int e = 0; e < cc; e++) {
                    float b0 = __shfl(a0, e), b1 = __shfl(a1, e);
                    float b2 = __shfl(a2, e), b3 = __shfl(a3, e);
                    int ce = __shfl(c, e);
                    float mya = hsel == 0 ? b0 : hsel == 1 ? b1 : hsel == 2 ? b2 : b3;
                    half4 cv = c4[(size_t)ce * 64 + lane];
                    acc.x += mya * (float)cv[0]; acc.y += mya * (float)cv[1];
                    acc.z += mya * (float)cv[2]; acc.w += mya * (float)cv[3];
                }
            }
            float4 bv = ((const float4*)bias)[lane];
            acc.x += bv.x; acc.y += bv.y; acc.z += bv.z; acc.w += bv.w;
            ((float4*)out)[(size_t)nn * 64 + lane] = acc;
        }
    }

    // gram: 6-stage wave reduce merges both halves (contributions are additive)
#pragma unroll
    for (int s = 1; s < 64; s <<= 1) {
#pragma unroll
        for (int k = 0; k < 10; k++) g[k] += __shfl_xor(g[k], s);
    }
    if (lane == 0) {
#pragma unroll
        for (int k = 0; k < 10; k++) atomicAdd(&gsh[k], g[k]);
    }
    __syncthreads();
    if (threadIdx.x < 10) gpart[(size_t)blockIdx.x * 10 + threadIdx.x] = gsh[threadIdx.x];
}

// ---------------- gram reduction + diversity loss ----------------
__global__ __launch_bounds__(1024) void k_final(const float* __restrict__ gpart,
                                                float* __restrict__ out_div) {
    __shared__ float s[1024];
    const int t = threadIdx.x;
    const int k = t & 15, grp = t >> 4;   // 64 groups x 16 slots
    float v = 0.f;
    if (k < 10) {
        for (int b = grp; b < NBLK; b += 64) v += gpart[(size_t)b * 10 + k];
    }
    s[t] = v;
    __syncthreads();
    for (int off = 512; off >= 16; off >>= 1) {
        if (t < off) s[t] += s[t + off];
        __syncthreads();
    }
    if (t == 0) {
        float g00 = s[0], g01 = s[1], g02 = s[2], g03 = s[3];
        float g11 = s[4], g12 = s[5], g13 = s[6];
        float g22 = s[7], g23 = s[8], g33 = s[9];
        float n0 = fmaxf(sqrtf(g00), 1e-8f), n1 = fmaxf(sqrtf(g11), 1e-8f);
        float n2 = fmaxf(sqrtf(g22), 1e-8f), n3 = fmaxf(sqrtf(g33), 1e-8f);
        float sum = g01 / (n0 * n1) + g02 / (n0 * n2) + g03 / (n0 * n3) +
                    g12 / (n1 * n2) + g13 / (n1 * n3) + g23 / (n2 * n3);
        sum *= 2.0f;
        out_div[0] = sum / 16.0f * 0.1f;
    }
}

extern "C" void kernel_launch(void* const* d_in, const int* in_sizes, int n_in,
                              void* d_out, int out_size, void* d_ws, size_t ws_size,
                              hipStream_t stream) {
    const float* x    = (const float*)d_in[0];
    const int*   ei   = (const int*)d_in[1];
    const int*   row  = ei;
    const int*   col  = ei + NE;
    const float* w    = (const float*)d_in[2];
    const float* att  = (const float*)d_in[3];
    const float* patt = (const float*)d_in[4];
    const float* bias = (const float*)d_in[5];
    float* out = (float*)d_out;

    char* p = (char*)d_ws;
    _Float16* content = (_Float16*)p; p += (size_t)NN * 256 * 2;
    _Float16* wfrag   = (_Float16*)p; p += (size_t)256 * 256 * 2;
    float* ssrc    = (float*)p; p += (size_t)NN * 4 * 4;
    float* sdst    = (float*)p; p += (size_t)NN * 4 * 4;
    float* gpart   = (float*)p; p += (size_t)NBLK * 10 * 4;
    int* counts    = (int*)p;   p += (size_t)NN * 4;
    int* direct    = (int*)p;   p += (size_t)NN * MAXDEG * 4;

    // zero counts in one graph-capturable memset node
    hipMemsetAsync(counts, 0, (size_t)NN * 4, stream);

    k_pc<<<(NE + 255) / 256, 256, 0, stream>>>(w, wfrag, row, col, counts, direct);

    k_gemm<<<(NN + GR - 1) / GR, 256, 0, stream>>>(x, wfrag, att, patt, content, ssrc, sdst);

    k_node<<<NBLK, 256, 0, stream>>>(content, ssrc, sdst, counts, direct,
                                     bias, out, gpart);
    k_final<<<1, 1024, 0, stream>>>(gpart, out + (size_t)NN * 256);
}

// Round 6
// 200.317 us; speedup vs baseline: 5.9293x; 1.1569x over previous
//
#include <hip/hip_runtime.h>
#include <math.h>

#define NN 50000
#define NE 500000
#define HH 4
#define CC 64
#define HC 256
#define PD 16
#define XD 272
#define NEG 0.2f
#define MAXDEG 64   // direct bucket row stride; Poisson(10) over 50000 draws -> max deg ~30
#define NBLK (NN / 8)   // k_node blocks (8 nodes / block, 2 per wave)
#define GR 32       // k_gb rows per tile (32 -> 1563 blocks, ~6 blocks/CU)
#define GBLK ((NN + GR - 1) / GR)   // 1563
#define GSZ  (GBLK * 256)           // 400128 threads in k_gb

typedef _Float16 half4 __attribute__((ext_vector_type(4)));
typedef _Float16 half8 __attribute__((ext_vector_type(8)));
typedef float floatx4 __attribute__((ext_vector_type(4)));

#define ASTR 272   // LDS A row stride in halves (MFMA-read conflict-free)
#define CSTR 256   // LDS content-tile stride in halves (XOR-swizzled)

// ---------------- wfrag swizzle: W -> fp16 MFMA-fragment order ----------------
// wfrag[(((kt*4+wv)*4+nt)*64 + lane)*8 + j] = W[wv*64+nt*16+(lane&15)][kt*32+(lane>>4)*8+j]
__global__ void k_w(const float* __restrict__ w, _Float16* __restrict__ wfrag) {
    int idx = blockIdx.x * blockDim.x + threadIdx.x;   // 65536 threads exactly
    int j = idx & 7, lane = (idx >> 3) & 63, nt = (idx >> 9) & 3;
    int wv = (idx >> 11) & 3, kt = idx >> 13;
    int n = wv * 64 + nt * 16 + (lane & 15);
    int k = kt * 32 + (lane >> 4) * 8 + j;
    wfrag[idx] = (_Float16)w[(size_t)n * 256 + k];
}

// ---------------- fused MFMA GEMM + edge bucketing ----------------
// GEMM: content(fp16) = Xc @ W^T + fused attention scores (as in R5).
// Edge bucketing fused in: each thread owns <=2 edges; atomicAdd issued BEFORE
// the MFMA body, dependent scatter store AFTER it -> the ~600cy atomic round
// trip hides under staging+MFMA instead of costing a standalone kernel.
__global__ __launch_bounds__(256) void k_gb(const float* __restrict__ x,
                                            const _Float16* __restrict__ wfrag,
                                            const float* __restrict__ att,
                                            const float* __restrict__ patt,
                                            const int* __restrict__ row,
                                            const int* __restrict__ col,
                                            int* __restrict__ counts,
                                            int* __restrict__ direct,
                                            _Float16* __restrict__ content,
                                            float* __restrict__ ssrc,
                                            float* __restrict__ sdst) {
    __shared__ _Float16 As[GR * ASTR];   // 17408 B; reused as Ct[32][CSTR] (16384 B)
    const int tid = threadIdx.x;
    const int wv = tid >> 6, lane = tid & 63;
    const int nb = blockIdx.x * GR;
    const int m16 = lane & 15, q = lane >> 4;

    // ---- edge phase A: loads + atomics issued early (latency hidden under GEMM) ----
    const int gid = blockIdx.x * 256 + tid;
    int r0 = -1, c0 = 0, s0e = MAXDEG, r1 = -1, c1 = 0, s1e = MAXDEG;
    {
        const int e1 = gid + GSZ;
        if (gid < NE) { r0 = row[gid]; c0 = col[gid]; }
        if (e1 < NE)  { r1 = row[e1];  c1 = col[e1]; }
        if (r0 >= 0) s0e = atomicAdd(&counts[r0], 1);
        if (r1 >= 0) s1e = atomicAdd(&counts[r1], 1);
    }

    // ---- stage A: thread t -> row t>>3, k-base (t&7)*32 (32 floats -> fp16) ----
    {
        const int rw = tid >> 3, kb = (tid & 7) * 32;
        int node = nb + rw; if (node >= NN) node = NN - 1;   // clamp; stores guarded later
        const float* xp = &x[(size_t)node * XD + kb];
        _Float16* ap = &As[rw * ASTR + kb];
#pragma unroll
        for (int i = 0; i < 4; i++) {
            float4 f0 = *(const float4*)(xp + i * 8);
            float4 f1 = *(const float4*)(xp + i * 8 + 4);
            half8 hv;
            hv[0] = (_Float16)f0.x; hv[1] = (_Float16)f0.y;
            hv[2] = (_Float16)f0.z; hv[3] = (_Float16)f0.w;
            hv[4] = (_Float16)f1.x; hv[5] = (_Float16)f1.y;
            hv[6] = (_Float16)f1.z; hv[7] = (_Float16)f1.w;
            *(half8*)(ap + i * 8) = hv;
        }
    }
    __syncthreads();

    floatx4 acc[2][4];
#pragma unroll
    for (int mt = 0; mt < 2; mt++)
#pragma unroll
        for (int nt = 0; nt < 4; nt++) acc[mt][nt] = (floatx4){0.f, 0.f, 0.f, 0.f};

#pragma unroll
    for (int kt = 0; kt < 8; kt++) {
        half8 bf[4];
#pragma unroll
        for (int nt = 0; nt < 4; nt++)
            bf[nt] = *(const half8*)&wfrag[((((size_t)kt * 4 + wv) * 4 + nt) * 64 + lane) * 8];
        half8 af[2];
#pragma unroll
        for (int mt = 0; mt < 2; mt++)
            af[mt] = *(half8*)&As[(mt * 16 + m16) * ASTR + kt * 32 + q * 8];
#pragma unroll
        for (int mt = 0; mt < 2; mt++)
#pragma unroll
            for (int nt = 0; nt < 4; nt++)
                acc[mt][nt] = __builtin_amdgcn_mfma_f32_16x16x32_f16(
                    af[mt], bf[nt], acc[mt][nt], 0, 0, 0);
    }

    // ---- edge phase B: dependent scatter stores (atomic results have landed) ----
    if (r0 >= 0 && s0e < MAXDEG) direct[(size_t)r0 * MAXDEG + s0e] = c0;
    if (r1 >= 0 && s1e < MAXDEG) direct[(size_t)r1 * MAXDEG + s1e] = c1;

    __syncthreads();   // all As reads done; safe to overwrite with Ct

    // ---- acc -> LDS content tile, fp16, XOR-swizzled: col ^= (node&7)<<3 ----
    // D layout: col(in head) = nt*16 + m16, node = mt*16 + q*4 + r
    _Float16* Ct = As;
#pragma unroll
    for (int mt = 0; mt < 2; mt++) {
#pragma unroll
        for (int nt = 0; nt < 4; nt++) {
#pragma unroll
            for (int r = 0; r < 4; r++) {
                int nl = mt * 16 + q * 4 + r;
                int cl = (wv * 64 + nt * 16 + m16) ^ ((nl & 7) << 3);
                Ct[nl * CSTR + cl] = (_Float16)acc[mt][nt][r];
            }
        }
    }
    __syncthreads();

    // ---- vectorized content store: thread covers row wv*8+(lane>>3), 64-B seg lane&7 ----
    {
        const int rowl = wv * 8 + (lane >> 3), seg = lane & 7;
        const int node = nb + rowl;
        if (node < NN) {
            _Float16* cp = &content[(size_t)node * 256 + seg * 32];
#pragma unroll
            for (int i = 0; i < 4; i++) {
                int colb = (seg * 32 + i * 8) ^ ((rowl & 7) << 3);
                *(half8*)(cp + i * 8) = *(const half8*)&Ct[rowl * CSTR + colb];
            }
        }
    }

    // ---- scores: lanes 0-31 -> sa for node el, lanes 32-63 -> sb for node el ----
    {
        const int el = lane & 31, hb = lane >> 5;
        const int node = nb + el;
        float s = 0.f;
        const float* ap = &att[wv * 128 + hb * 64];
#pragma unroll
        for (int i = 0; i < 8; i++) {
            int colb = (wv * 64 + i * 8) ^ ((el & 7) << 3);
            half8 v = *(const half8*)&Ct[el * CSTR + colb];
#pragma unroll
            for (int j = 0; j < 8; j++) s += (float)v[j] * ap[i * 8 + j];
        }
        const int rn = node < NN ? node : NN - 1;
        const float* xp = &x[(size_t)rn * XD + 256];
        const float* pp = &patt[wv * 32 + hb * 16];
#pragma unroll
        for (int p4 = 0; p4 < 4; p4++) {
            float4 pv = *(const float4*)(xp + p4 * 4);
            s += pv.x * pp[p4 * 4 + 0] + pv.y * pp[p4 * 4 + 1]
               + pv.z * pp[p4 * 4 + 2] + pv.w * pp[p4 * 4 + 3];
        }
        if (node < NN) {
            float* dst = hb ? sdst : ssrc;
            dst[node * 4 + wv] = s;
        }
    }
}

// ---------------- per-node softmax + aggregation (2 nodes / wave, 32 lanes each) ----------------
// Node A = lanes 0-31, node B = lanes 32-63. Gathers are half8 (16 B/lane).
// Software pipeline: batch-0 gathers issued BEFORE the softmax math; agg loop
// prefetches batch k+1 while FMA-ing batch k (8 rows in flight/wave).
// Gram partials: bucketed global atomics into gbuf[64][10] (contention ~98
// blocks/bucket over 54 us -- NOT the R4 fence pattern; no __threadfence).
__global__ __launch_bounds__(256) void k_node(const _Float16* __restrict__ content,
                                              const float* __restrict__ ssrc,
                                              const float* __restrict__ sdst,
                                              const int* __restrict__ counts,
                                              const int* __restrict__ direct,
                                              const float* __restrict__ bias,
                                              float* __restrict__ out,
                                              float* __restrict__ gbuf) {
    __shared__ float gsh[16];
    __shared__ __align__(16) float ash[4][2][4][32];  // [wave][half][head][edge]
    __shared__ __align__(16) int   csh[4][2][32];     // per-half col cache
    const int w = threadIdx.x >> 6;
    const int lane = threadIdx.x & 63;
    const int h2 = lane >> 5, el = lane & 31;
    const int nb2 = blockIdx.x * 8 + w * 2;   // NN % 8 == 0
    if (threadIdx.x < 16) gsh[threadIdx.x] = 0.f;
    __syncthreads();

    const int n = nb2 + h2;
    const int cnt = counts[n];              // broadcast 4B load per half

    float g[10];
#pragma unroll
    for (int k = 0; k < 10; k++) g[k] = 0.f;

    if (__all(cnt < 32)) {
        // ---- fast path: one edge per lane within each 32-lane half ----
        const int tot = cnt + 1;                 // + self loop
        const bool act = el < tot;
        const int c = (el < cnt) ? direct[(size_t)n * MAXDEG + el] : n;  // pad = self
        csh[w][h2][el] = c;                      // publish indices FIRST

        // issue batch-0 gathers before softmax math (latency overlap)
        const half8* c8 = (const half8*)content;
        const int4 ca0 = *(const int4*)&csh[w][h2][0];
        half8 v0 = c8[(size_t)ca0.x * 32 + el];
        half8 v1 = c8[(size_t)ca0.y * 32 + el];
        half8 v2 = c8[(size_t)ca0.z * 32 + el];
        half8 v3 = c8[(size_t)ca0.w * 32 + el];

        const float4 ss = *(const float4*)&ssrc[n * 4];
        const float4 sd = *(const float4*)&sdst[c * 4];
        float r0 = ss.x + sd.x; r0 = r0 > 0.f ? r0 : NEG * r0;
        float r1 = ss.y + sd.y; r1 = r1 > 0.f ? r1 : NEG * r1;
        float r2 = ss.z + sd.z; r2 = r2 > 0.f ? r2 : NEG * r2;
        float r3 = ss.w + sd.w; r3 = r3 > 0.f ? r3 : NEG * r3;
        float e0 = act ? __expf(r0) : 0.f;       // no max-subtract: |r| bounded
        float e1 = act ? __expf(r1) : 0.f;
        float e2 = act ? __expf(r2) : 0.f;
        float e3 = act ? __expf(r3) : 0.f;
        float s0 = e0, s1 = e1, s2 = e2, s3 = e3;
#pragma unroll
        for (int s = 1; s < 32; s <<= 1) {      // within-half reduce
            s0 += __shfl_xor(s0, s); s1 += __shfl_xor(s1, s);
            s2 += __shfl_xor(s2, s); s3 += __shfl_xor(s3, s);
        }
        const float a0 = e0 / (s0 + 1e-16f), a1 = e1 / (s1 + 1e-16f);
        const float a2 = e2 / (s2 + 1e-16f), a3 = e3 / (s3 + 1e-16f);

        g[0] = a0 * a0; g[1] = a0 * a1; g[2] = a0 * a2; g[3] = a0 * a3;
        g[4] = a1 * a1; g[5] = a1 * a2; g[6] = a1 * a3;
        g[7] = a2 * a2; g[8] = a2 * a3; g[9] = a3 * a3;

        ash[w][h2][0][el] = a0; ash[w][h2][1][el] = a1;
        ash[w][h2][2][el] = a2; ash[w][h2][3][el] = a3;

        // ---- aggregation: lane covers channels el*8..el*8+7; prefetch next batch ----
        const int hd = el >> 3;
        float acc[8];
#pragma unroll
        for (int j = 0; j < 8; j++) acc[j] = 0.f;

        const int nit = (tot + 3) & ~3;
        for (int e = 0; e < nit; e += 4) {
            const half8 w0 = v0, w1 = v1, w2 = v2, w3 = v3;
            if (e + 4 < nit) {
                const int4 cn = *(const int4*)&csh[w][h2][e + 4];
                v0 = c8[(size_t)cn.x * 32 + el];
                v1 = c8[(size_t)cn.y * 32 + el];
                v2 = c8[(size_t)cn.z * 32 + el];
                v3 = c8[(size_t)cn.w * 32 + el];
            }
            const float4 ba = *(const float4*)&ash[w][h2][hd][e];
#pragma unroll
            for (int j = 0; j < 8; j++)
                acc[j] += ba.x * (float)w0[j] + ba.y * (float)w1[j]
                        + ba.z * (float)w2[j] + ba.w * (float)w3[j];
        }

        const float4 bv0 = ((const float4*)bias)[el * 2];
        const float4 bv1 = ((const float4*)bias)[el * 2 + 1];
        float4 o0, o1;
        o0.x = acc[0] + bv0.x; o0.y = acc[1] + bv0.y;
        o0.z = acc[2] + bv0.z; o0.w = acc[3] + bv0.w;
        o1.x = acc[4] + bv1.x; o1.y = acc[5] + bv1.y;
        o1.z = acc[6] + bv1.z; o1.w = acc[7] + bv1.w;
        ((float4*)out)[(size_t)n * 64 + el * 2] = o0;
        ((float4*)out)[(size_t)n * 64 + el * 2 + 1] = o1;
    } else {
        // ---- generic chunked path (degree >= 32; essentially never) ----
        // whole wave processes each of the 2 nodes sequentially
        const int hsel = lane >> 4;
        const half4* c4 = (const half4*)content;
        for (int sN = 0; sN < 2; sN++) {
            const int nn = nb2 + sN;
            int cnt2 = counts[nn]; if (cnt2 > MAXDEG) cnt2 = MAXDEG;
            const int total = cnt2 + 1;
            const size_t base2 = (size_t)nn * MAXDEG;
            const float4 ss = *(const float4*)&ssrc[nn * 4];
            float4 acc = make_float4(0.f, 0.f, 0.f, 0.f);
            const int nch = (total + 63) >> 6;
            float m0 = -1e30f, m1 = -1e30f, m2 = -1e30f, m3 = -1e30f;
            for (int ch = 0; ch < nch; ch++) {
                int l = ch * 64 + lane;
                if (l < total) {
                    int c = (l < cnt2) ? direct[base2 + l] : nn;
                    float4 sd = *(const float4*)&sdst[c * 4];
                    float r0 = ss.x + sd.x; r0 = r0 > 0.f ? r0 : NEG * r0;
                    float r1 = ss.y + sd.y; r1 = r1 > 0.f ? r1 : NEG * r1;
                    float r2 = ss.z + sd.z; r2 = r2 > 0.f ? r2 : NEG * r2;
                    float r3 = ss.w + sd.w; r3 = r3 > 0.f ? r3 : NEG * r3;
                    m0 = fmaxf(m0, r0); m1 = fmaxf(m1, r1);
                    m2 = fmaxf(m2, r2); m3 = fmaxf(m3, r3);
                }
            }
#pragma unroll
            for (int s = 1; s < 64; s <<= 1) {
                m0 = fmaxf(m0, __shfl_xor(m0, s));
                m1 = fmaxf(m1, __shfl_xor(m1, s));
                m2 = fmaxf(m2, __shfl_xor(m2, s));
                m3 = fmaxf(m3, __shfl_xor(m3, s));
            }
            float s0 = 0.f, s1 = 0.f, s2 = 0.f, s3 = 0.f;
            for (int ch = 0; ch < nch; ch++) {
                int l = ch * 64 + lane;
                if (l < total) {
                    int c = (l < cnt2) ? direct[base2 + l] : nn;
                    float4 sd = *(const float4*)&sdst[c * 4];
                    float r0 = ss.x + sd.x; r0 = r0 > 0.f ? r0 : NEG * r0;
                    float r1 = ss.y + sd.y; r1 = r1 > 0.f ? r1 : NEG * r1;
                    float r2 = ss.z + sd.z; r2 = r2 > 0.f ? r2 : NEG * r2;
                    float r3 = ss.w + sd.w; r3 = r3 > 0.f ? r3 : NEG * r3;
                    s0 += __expf(r0 - m0); s1 += __expf(r1 - m1);
                    s2 += __expf(r2 - m2); s3 += __expf(r3 - m3);
                }
            }
#pragma unroll
            for (int s = 1; s < 64; s <<= 1) {
                s0 += __shfl_xor(s0, s); s1 += __shfl_xor(s1, s);
                s2 += __shfl_xor(s2, s); s3 += __shfl_xor(s3, s);
            }
            const float i0 = 1.f / (s0 + 1e-16f), i1 = 1.f / (s1 + 1e-16f);
            const float i2 = 1.f / (s2 + 1e-16f), i3 = 1.f / (s3 + 1e-16f);

            for (int ch = 0; ch < nch; ch++) {
                int l = ch * 64 + lane;
                int c = nn;
                float a0 = 0.f, a1 = 0.f, a2 = 0.f, a3 = 0.f;
                if (l < total) {
                    c = (l < cnt2) ? direct[base2 + l] : nn;
                    float4 sd = *(const float4*)&sdst[c * 4];
                    float r0 = ss.x + sd.x; r0 = r0 > 0.f ? r0 : NEG * r0;
                    float r1 = ss.y + sd.y; r1 = r1 > 0.f ? r1 : NEG * r1;
                    float r2 = ss.z + sd.z; r2 = r2 > 0.f ? r2 : NEG * r2;
                    float r3 = ss.w + sd.w; r3 = r3 > 0.f ? r3 : NEG * r3;
                    a0 = __expf(r0 - m0) * i0; a1 = __expf(r1 - m1) * i1;
                    a2 = __expf(r2 - m2) * i2; a3 = __expf(r3 - m3) * i3;
                }
                g[0] += a0 * a0; g[1] += a0 * a1; g[2] += a0 * a2; g[3] += a0 * a3;
                g[4] += a1 * a1; g[5] += a1 * a2; g[6] += a1 * a3;
                g[7] += a2 * a2; g[8] += a2 * a3; g[9] += a3 * a3;

                int cc = min(64, total - ch * 64);
                for (int e = 0; e < cc; e++) {
                    float b0 = __shfl(a0, e), b1 = __shfl(a1, e);
                    float b2 = __shfl(a2, e), b3 = __shfl(a3, e);
                    int ce = __shfl(c, e);
                    float mya = hsel == 0 ? b0 : hsel == 1 ? b1 : hsel == 2 ? b2 : b3;
                    half4 cv = c4[(size_t)ce * 64 + lane];
                    acc.x += mya * (float)cv[0]; acc.y += mya * (float)cv[1];
                    acc.z += mya * (float)cv[2]; acc.w += mya * (float)cv[3];
                }
            }
            float4 bv = ((const float4*)bias)[lane];
            acc.x += bv.x; acc.y += bv.y; acc.z += bv.z; acc.w += bv.w;
            ((float4*)out)[(size_t)nn * 64 + lane] = acc;
        }
    }

    // gram: 6-stage wave reduce merges both halves (contributions are additive)
#pragma unroll
    for (int s = 1; s < 64; s <<= 1) {
#pragma unroll
        for (int k = 0; k < 10; k++) g[k] += __shfl_xor(g[k], s);
    }
    if (lane == 0) {
#pragma unroll
        for (int k = 0; k < 10; k++) atomicAdd(&gsh[k], g[k]);
    }
    __syncthreads();
    if (threadIdx.x < 10)
        atomicAdd(&gbuf[(blockIdx.x & 63) * 10 + threadIdx.x], gsh[threadIdx.x]);
}

// ---------------- gram reduction + diversity loss (single wave) ----------------
__global__ void k_final(const float* __restrict__ gbuf, float* __restrict__ out_div) {
    const int lane = threadIdx.x;   // 64 threads, 1 block
    float g[10];
#pragma unroll
    for (int k = 0; k < 10; k++) g[k] = gbuf[lane * 10 + k];
#pragma unroll
    for (int s = 1; s < 64; s <<= 1) {
#pragma unroll
        for (int k = 0; k < 10; k++) g[k] += __shfl_xor(g[k], s);
    }
    if (lane == 0) {
        float n0 = fmaxf(sqrtf(g[0]), 1e-8f), n1 = fmaxf(sqrtf(g[4]), 1e-8f);
        float n2 = fmaxf(sqrtf(g[7]), 1e-8f), n3 = fmaxf(sqrtf(g[9]), 1e-8f);
        float sum = g[1] / (n0 * n1) + g[2] / (n0 * n2) + g[3] / (n0 * n3) +
                    g[5] / (n1 * n2) + g[6] / (n1 * n3) + g[8] / (n2 * n3);
        sum *= 2.0f;
        out_div[0] = sum / 16.0f * 0.1f;
    }
}

extern "C" void kernel_launch(void* const* d_in, const int* in_sizes, int n_in,
                              void* d_out, int out_size, void* d_ws, size_t ws_size,
                              hipStream_t stream) {
    const float* x    = (const float*)d_in[0];
    const int*   ei   = (const int*)d_in[1];
    const int*   row  = ei;
    const int*   col  = ei + NE;
    const float* w    = (const float*)d_in[2];
    const float* att  = (const float*)d_in[3];
    const float* patt = (const float*)d_in[4];
    const float* bias = (const float*)d_in[5];
    float* out = (float*)d_out;

    char* p = (char*)d_ws;
    _Float16* content = (_Float16*)p; p += (size_t)NN * 256 * 2;
    _Float16* wfrag   = (_Float16*)p; p += (size_t)256 * 256 * 2;
    float* ssrc    = (float*)p; p += (size_t)NN * 4 * 4;
    float* sdst    = (float*)p; p += (size_t)NN * 4 * 4;
    int* counts    = (int*)p;   p += (size_t)NN * 4;
    float* gbuf    = (float*)p; p += 64 * 10 * 4;       // contiguous with counts: one memset
    int* direct    = (int*)p;   p += (size_t)NN * MAXDEG * 4;

    // zero counts + gbuf in one graph-capturable memset node
    hipMemsetAsync(counts, 0, (size_t)NN * 4 + 64 * 10 * 4, stream);

    k_w<<<256, 256, 0, stream>>>(w, wfrag);

    k_gb<<<GBLK, 256, 0, stream>>>(x, wfrag, att, patt, row, col, counts, direct,
                                   content, ssrc, sdst);

    k_node<<<NBLK, 256, 0, stream>>>(content, ssrc, sdst, counts, direct,
                                     bias, out, gbuf);
    k_final<<<1, 64, 0, stream>>>(gbuf, out + (size_t)NN * 256);
}